// Round 3
// baseline (132.275 us; speedup 1.0000x reference)
//
#include <hip/hip_runtime.h>
#include <stdint.h>

#define N_G   1024
#define H_IMG 128
#define W_IMG 128
#define TILE  8
#define TILES_X (W_IMG / TILE)            // 16
#define N_TILES (TILES_X * (H_IMG/TILE))  // 256
#define FXc   128.0f
#define FYc   128.0f

// ws layout (floats):
//   payload[1024*12]        (48B records: gx,gy,A,B | C,op,r,g | b,rc2,0,0)
//   sorted_payload[1024*12]
//   keys u64[1024]
#define WS_PAY    0
#define WS_SORTED (N_G*12)
#define WS_KEYS   (N_G*24)

// ---------------- Kernel 1: per-gaussian preprocess ----------------
__global__ __launch_bounds__(256) void prep_kernel(
    const float* __restrict__ means3D, const float* __restrict__ opac,
    const float* __restrict__ shs,     const float* __restrict__ scales,
    const float* __restrict__ rot,     const float* __restrict__ vm,
    const float* __restrict__ pm,      const float* __restrict__ campos,
    float* __restrict__ radii_out,     float4* __restrict__ payload,
    unsigned long long* __restrict__ keys)
{
    const int n = blockIdx.x * 256 + threadIdx.x;
    if (n >= N_G) return;

    float mx = means3D[n*3+0], my = means3D[n*3+1], mz = means3D[n*3+2];

    float pv0   = mx*vm[0] + my*vm[4] + mz*vm[8]  + vm[12];
    float pv1   = mx*vm[1] + my*vm[5] + mz*vm[9]  + vm[13];
    float depth = mx*vm[2] + my*vm[6] + mz*vm[10] + vm[14];
    bool dvalid = depth > 0.2f;

    float ph0 = mx*pm[0] + my*pm[4] + mz*pm[8]  + pm[12];
    float ph1 = mx*pm[1] + my*pm[5] + mz*pm[9]  + pm[13];
    float ph3 = mx*pm[3] + my*pm[7] + mz*pm[11] + pm[15];
    float invw = 1.0f / (ph3 + 1e-7f);
    float pp0 = ph0 * invw, pp1 = ph1 * invw;

    float4 q = *(const float4*)(rot + n*4);
    float qn = sqrtf(q.x*q.x + q.y*q.y + q.z*q.z + q.w*q.w);
    float qr = q.x/qn, qx = q.y/qn, qy = q.z/qn, qz = q.w/qn;
    float R00 = 1.f - 2.f*(qy*qy + qz*qz), R01 = 2.f*(qx*qy - qr*qz), R02 = 2.f*(qx*qz + qr*qy);
    float R10 = 2.f*(qx*qy + qr*qz), R11 = 1.f - 2.f*(qx*qx + qz*qz), R12 = 2.f*(qy*qz - qr*qx);
    float R20 = 2.f*(qx*qz - qr*qy), R21 = 2.f*(qy*qz + qr*qx), R22 = 1.f - 2.f*(qx*qx + qy*qy);

    float s0 = scales[n*3+0], s1 = scales[n*3+1], s2 = scales[n*3+2];
    float M00=R00*s0, M01=R01*s1, M02=R02*s2;
    float M10=R10*s0, M11=R11*s1, M12=R12*s2;
    float M20=R20*s0, M21=R21*s1, M22=R22*s2;

    float S00 = M00*M00 + M01*M01 + M02*M02;
    float S01 = M00*M10 + M01*M11 + M02*M12;
    float S02 = M00*M20 + M01*M21 + M02*M22;
    float S11 = M10*M10 + M11*M11 + M12*M12;
    float S12 = M10*M20 + M11*M21 + M12*M22;
    float S22 = M20*M20 + M21*M21 + M22*M22;

    float tz   = dvalid ? depth : 1.0f;
    float txtz = fminf(fmaxf(pv0 / tz, -0.65f), 0.65f) * tz;
    float tytz = fminf(fmaxf(pv1 / tz, -0.65f), 0.65f) * tz;
    float J00 = FXc / tz, J02 = -FXc * txtz / (tz*tz);
    float J11 = FYc / tz, J12 = -FYc * tytz / (tz*tz);

    float T20k0 = J00*vm[0] + J02*vm[2];
    float T20k1 = J00*vm[4] + J02*vm[6];
    float T20k2 = J00*vm[8] + J02*vm[10];
    float T21k0 = J11*vm[1] + J12*vm[2];
    float T21k1 = J11*vm[5] + J12*vm[6];
    float T21k2 = J11*vm[9] + J12*vm[10];

    float U00 = T20k0*S00 + T20k1*S01 + T20k2*S02;
    float U01 = T20k0*S01 + T20k1*S11 + T20k2*S12;
    float U02 = T20k0*S02 + T20k1*S12 + T20k2*S22;
    float U10 = T21k0*S00 + T21k1*S01 + T21k2*S02;
    float U11 = T21k0*S01 + T21k1*S11 + T21k2*S12;
    float U12 = T21k0*S02 + T21k1*S12 + T21k2*S22;
    float cov00 = U00*T20k0 + U01*T20k1 + U02*T20k2;
    float cov01 = U00*T21k0 + U01*T21k1 + U02*T21k2;
    float cov11 = U10*T21k0 + U11*T21k1 + U12*T21k2;

    float a = cov00 + 0.3f, b = cov01, c = cov11 + 0.3f;
    float det = a*c - b*b;
    bool valid = dvalid && (det > 0.0f);
    float inv_det = (det > 0.0f) ? (1.0f / det) : 1.0f;
    float conA = c * inv_det, conB = -b * inv_det, conC = a * inv_det;

    float mid  = 0.5f * (a + c);
    float lam1 = mid + sqrtf(fmaxf(0.1f, mid*mid - det));
    radii_out[n] = valid ? ceilf(3.0f * sqrtf(lam1)) : 0.0f;

    float gx = ((pp0 + 1.0f) * (float)W_IMG - 1.0f) * 0.5f;
    float gy = ((pp1 + 1.0f) * (float)H_IMG - 1.0f) * 0.5f;

    float dxm = mx - campos[0], dym = my - campos[1], dzm = mz - campos[2];
    float dn = sqrtf(dxm*dxm + dym*dym + dzm*dzm);
    float sx = dxm/dn, sy = dym/dn, sz = dzm/dn;
    float xx = sx*sx, yy = sy*sy, zz = sz*sz;
    float xy = sx*sy, yz = sy*sz, xz = sx*sz;
    // SH loads as float4 (n*48 floats is 16B aligned): sh4[k].{x,y,z,w} = sh flat
    const float4* sh4 = (const float4*)(shs + n*48);
    float shf[48];
    #pragma unroll
    for (int k = 0; k < 12; ++k) {
        float4 v = sh4[k];
        shf[k*4+0]=v.x; shf[k*4+1]=v.y; shf[k*4+2]=v.z; shf[k*4+3]=v.w;
    }
    float col[3];
    #pragma unroll
    for (int ch = 0; ch < 3; ++ch) {
        float res = 0.28209479177387814f * shf[0*3+ch]
            - 0.4886025119029199f * sy * shf[1*3+ch]
            + 0.4886025119029199f * sz * shf[2*3+ch]
            - 0.4886025119029199f * sx * shf[3*3+ch]
            + 1.0925484305920792f  * xy * shf[4*3+ch]
            + (-1.0925484305920792f) * yz * shf[5*3+ch]
            + 0.31539156525252005f * (2.f*zz - xx - yy) * shf[6*3+ch]
            + (-1.0925484305920792f) * xz * shf[7*3+ch]
            + 0.5462742152960396f  * (xx - yy) * shf[8*3+ch]
            + (-0.5900435899266435f) * sy * (3.f*xx - yy) * shf[9*3+ch]
            + 2.890611442640554f   * xy * sz * shf[10*3+ch]
            + (-0.4570457994644658f) * sy * (4.f*zz - xx - yy) * shf[11*3+ch]
            + 0.3731763325901154f  * sz * (2.f*zz - 3.f*xx - 3.f*yy) * shf[12*3+ch]
            + (-0.4570457994644658f) * sx * (4.f*zz - xx - yy) * shf[13*3+ch]
            + 1.445305721320277f   * sz * (xx - yy) * shf[14*3+ch]
            + (-0.5900435899266435f) * sx * (xx - 3.f*yy) * shf[15*3+ch];
        col[ch] = fmaxf(res + 0.5f, 0.0f);
    }

    float op = opac[n];
    // conservative cull radius^2: alpha >= 1/255 needs |d|^2 <= 2 ln(255 op) lam1
    float op255 = op * 255.0f;
    float rc2 = (valid && op255 > 1.0f) ? (2.0f * logf(op255) * lam1 * 1.01f + 1.0f)
                                        : -1.0f;

    payload[n*3+0] = make_float4(gx, gy, conA, conB);
    payload[n*3+1] = make_float4(conC, op, col[0], col[1]);
    payload[n*3+2] = make_float4(col[2], rc2, 0.f, 0.f);

    unsigned int kb = valid ? __float_as_uint(depth) : 0x7F800000u; // depth>0.2 => positive
    keys[n] = ((unsigned long long)kb << 32) | (unsigned int)n;
}

// ---------------- Kernel 2: barrier-free rank sort + scatter ----------------
__global__ __launch_bounds__(256) void rank_sort_kernel(
    const unsigned long long* __restrict__ keys,
    const float4* __restrict__ payload,
    float4* __restrict__ sorted_payload)
{
    const int n = blockIdx.x * 256 + threadIdx.x;
    if (n >= N_G) return;
    unsigned long long mine = keys[n];
    int rank = 0;
    #pragma unroll 8
    for (int j = 0; j < N_G; ++j)
        rank += (keys[j] < mine) ? 1 : 0;    // keys unique (idx in low bits)
    float4 p0 = payload[n*3+0], p1 = payload[n*3+1], p2 = payload[n*3+2];
    sorted_payload[rank*3+0] = p0;
    sorted_payload[rank*3+1] = p1;
    sorted_payload[rank*3+2] = p2;
}

// ---------------- Kernel 3: per-tile streaming cull + blend (1 wave / 8x8 tile) ----------------
__global__ __launch_bounds__(64) void raster_tile(
    const float4* __restrict__ pay,       // sorted, 3 float4 per gaussian
    const float* __restrict__ bg,
    float* __restrict__ out)
{
    __shared__ float batch[64 * 16];      // stride 16 floats (bank-friendly)

    const int lane = threadIdx.x;
    const int tile = blockIdx.x;
    const int tx = tile & (TILES_X - 1), ty = tile / TILES_X;
    const float x0 = (float)(tx * TILE), x1 = x0 + (float)(TILE - 1);
    const float y0 = (float)(ty * TILE), y1 = y0 + (float)(TILE - 1);
    const float px = x0 + (float)(lane & (TILE - 1));
    const float py = y0 + (float)(lane / TILE);

    float T = 1.0f, Tfin = 1.0f, cr = 0.f, cg = 0.f, cb = 0.f;
    bool live = true;

    // prefetch chunk 0
    float4 a0 = pay[lane*3+0], a1 = pay[lane*3+1], a2 = pay[lane*3+2];

    for (int base = 0; base < N_G; base += 64) {
        // prefetch next chunk while we process this one
        float4 n0, n1, n2;
        const bool more = (base + 64) < N_G;
        if (more) {
            const float4* np = pay + (base + 64 + lane) * 3;
            n0 = np[0]; n1 = np[1]; n2 = np[2];
        }

        // cull test from registers (rc2 in a2.y; invalid records have rc2 = -1)
        float cx = fminf(fmaxf(a0.x, x0), x1) - a0.x;
        float cy = fminf(fmaxf(a0.y, y0), y1) - a0.y;
        bool pass = (cx*cx + cy*cy) <= a2.y;
        unsigned long long mask = __ballot(pass);

        if (mask != 0ull) {
            int pos = __popcll(mask & ((1ull << lane) - 1ull));
            if (pass) {
                float4* bp = (float4*)(batch + pos * 16);
                bp[0] = a0; bp[1] = a1; bp[2] = a2;
            }
            __syncthreads();
            int nb = __popcll(mask);
            for (int j = 0; j < nb; ++j) {
                float4 g0 = *(const float4*)(batch + j * 16);      // gx gy A B
                float4 g1 = *(const float4*)(batch + j * 16 + 4);  // C op r g
                float  b2 = batch[j * 16 + 8];                     // b
                float dx = g0.x - px, dy = g0.y - py;
                float power = -0.5f * (g0.z*dx*dx + g1.x*dy*dy) - g0.w*dx*dy;
                float alpha = fminf(0.99f, g1.y * expf(power));
                if (live && power <= 0.0f && alpha >= (1.0f/255.0f)) {
                    float Tnew = T * (1.0f - alpha);
                    if (Tnew < 1e-4f) {
                        live = false;          // exact: ae_i and all later ae are 0
                    } else {
                        float w = T * alpha;
                        cr += w * g1.z; cg += w * g1.w; cb += w * b2;
                        Tfin *= (1.0f - alpha);
                        T = Tnew;
                    }
                }
            }
            __syncthreads();
            if (__ballot(live) == 0ull) break;
        }

        a0 = n0; a1 = n1; a2 = n2;
    }

    int p = (int)py * W_IMG + (int)px;
    out[p]                 = cr + bg[0] * Tfin;
    out[H_IMG*W_IMG + p]   = cg + bg[1] * Tfin;
    out[2*H_IMG*W_IMG + p] = cb + bg[2] * Tfin;
}

extern "C" void kernel_launch(void* const* d_in, const int* in_sizes, int n_in,
                              void* d_out, int out_size, void* d_ws, size_t ws_size,
                              hipStream_t stream) {
    const float* means3D = (const float*)d_in[0];
    const float* opac    = (const float*)d_in[2];
    const float* shs     = (const float*)d_in[3];
    const float* scales  = (const float*)d_in[4];
    const float* rot     = (const float*)d_in[5];
    const float* vm      = (const float*)d_in[6];
    const float* pm      = (const float*)d_in[7];
    const float* campos  = (const float*)d_in[8];
    const float* bg      = (const float*)d_in[9];

    float* out = (float*)d_out;
    float* wsf = (float*)d_ws;
    float4*             payload = (float4*)(wsf + WS_PAY);
    float4*             sorted  = (float4*)(wsf + WS_SORTED);
    unsigned long long* keys    = (unsigned long long*)(wsf + WS_KEYS);

    prep_kernel<<<N_G/256, 256, 0, stream>>>(means3D, opac, shs, scales, rot,
                                             vm, pm, campos,
                                             out + 3*H_IMG*W_IMG, payload, keys);
    rank_sort_kernel<<<N_G/256, 256, 0, stream>>>(keys, payload, sorted);
    raster_tile<<<N_TILES, 64, 0, stream>>>(sorted, bg, out);
}

// Round 4
// 103.472 us; speedup vs baseline: 1.2784x; 1.2784x over previous
//
#include <hip/hip_runtime.h>
#include <stdint.h>

#define N_G   1024
#define H_IMG 128
#define W_IMG 128
#define TILE  8
#define TILES_X (W_IMG / TILE)            // 16
#define N_TILES (TILES_X * (H_IMG/TILE))  // 256
#define FXc   128.0f
#define FYc   128.0f

// ws layout (floats):
//   payload[1024*12]  (48B records: gx,gy,A,B | C,op,r,g | b,rc2,0,0)
//   sorted_payload[1024*12]
//   keys u64[1024]
#define WS_PAY    0
#define WS_SORTED (N_G*12)
#define WS_KEYS   (N_G*24)

// ---------------- Kernel 1: per-gaussian preprocess ----------------
__global__ __launch_bounds__(64) void prep_kernel(
    const float* __restrict__ means3D, const float* __restrict__ opac,
    const float* __restrict__ shs,     const float* __restrict__ scales,
    const float* __restrict__ rot,     const float* __restrict__ vm,
    const float* __restrict__ pm,      const float* __restrict__ campos,
    float* __restrict__ radii_out,     float4* __restrict__ payload,
    unsigned long long* __restrict__ keys)
{
    const int n = blockIdx.x * 64 + threadIdx.x;
    if (n >= N_G) return;

    float mx = means3D[n*3+0], my = means3D[n*3+1], mz = means3D[n*3+2];

    float pv0   = mx*vm[0] + my*vm[4] + mz*vm[8]  + vm[12];
    float pv1   = mx*vm[1] + my*vm[5] + mz*vm[9]  + vm[13];
    float depth = mx*vm[2] + my*vm[6] + mz*vm[10] + vm[14];
    bool dvalid = depth > 0.2f;

    float ph0 = mx*pm[0] + my*pm[4] + mz*pm[8]  + pm[12];
    float ph1 = mx*pm[1] + my*pm[5] + mz*pm[9]  + pm[13];
    float ph3 = mx*pm[3] + my*pm[7] + mz*pm[11] + pm[15];
    float invw = 1.0f / (ph3 + 1e-7f);
    float pp0 = ph0 * invw, pp1 = ph1 * invw;

    float4 q = *(const float4*)(rot + n*4);
    float qn = sqrtf(q.x*q.x + q.y*q.y + q.z*q.z + q.w*q.w);
    float qr = q.x/qn, qx = q.y/qn, qy = q.z/qn, qz = q.w/qn;
    float R00 = 1.f - 2.f*(qy*qy + qz*qz), R01 = 2.f*(qx*qy - qr*qz), R02 = 2.f*(qx*qz + qr*qy);
    float R10 = 2.f*(qx*qy + qr*qz), R11 = 1.f - 2.f*(qx*qx + qz*qz), R12 = 2.f*(qy*qz - qr*qx);
    float R20 = 2.f*(qx*qz - qr*qy), R21 = 2.f*(qy*qz + qr*qx), R22 = 1.f - 2.f*(qx*qx + qy*qy);

    float s0 = scales[n*3+0], s1 = scales[n*3+1], s2 = scales[n*3+2];
    float M00=R00*s0, M01=R01*s1, M02=R02*s2;
    float M10=R10*s0, M11=R11*s1, M12=R12*s2;
    float M20=R20*s0, M21=R21*s1, M22=R22*s2;

    float S00 = M00*M00 + M01*M01 + M02*M02;
    float S01 = M00*M10 + M01*M11 + M02*M12;
    float S02 = M00*M20 + M01*M21 + M02*M22;
    float S11 = M10*M10 + M11*M11 + M12*M12;
    float S12 = M10*M20 + M11*M21 + M12*M22;
    float S22 = M20*M20 + M21*M21 + M22*M22;

    float tz   = dvalid ? depth : 1.0f;
    float txtz = fminf(fmaxf(pv0 / tz, -0.65f), 0.65f) * tz;
    float tytz = fminf(fmaxf(pv1 / tz, -0.65f), 0.65f) * tz;
    float J00 = FXc / tz, J02 = -FXc * txtz / (tz*tz);
    float J11 = FYc / tz, J12 = -FYc * tytz / (tz*tz);

    float T20k0 = J00*vm[0] + J02*vm[2];
    float T20k1 = J00*vm[4] + J02*vm[6];
    float T20k2 = J00*vm[8] + J02*vm[10];
    float T21k0 = J11*vm[1] + J12*vm[2];
    float T21k1 = J11*vm[5] + J12*vm[6];
    float T21k2 = J11*vm[9] + J12*vm[10];

    float U00 = T20k0*S00 + T20k1*S01 + T20k2*S02;
    float U01 = T20k0*S01 + T20k1*S11 + T20k2*S12;
    float U02 = T20k0*S02 + T20k1*S12 + T20k2*S22;
    float U10 = T21k0*S00 + T21k1*S01 + T21k2*S02;
    float U11 = T21k0*S01 + T21k1*S11 + T21k2*S12;
    float U12 = T21k0*S02 + T21k1*S12 + T21k2*S22;
    float cov00 = U00*T20k0 + U01*T20k1 + U02*T20k2;
    float cov01 = U00*T21k0 + U01*T21k1 + U02*T21k2;
    float cov11 = U10*T21k0 + U11*T21k1 + U12*T21k2;

    float a = cov00 + 0.3f, b = cov01, c = cov11 + 0.3f;
    float det = a*c - b*b;
    bool valid = dvalid && (det > 0.0f);
    float inv_det = (det > 0.0f) ? (1.0f / det) : 1.0f;
    float conA = c * inv_det, conB = -b * inv_det, conC = a * inv_det;

    float mid  = 0.5f * (a + c);
    float lam1 = mid + sqrtf(fmaxf(0.1f, mid*mid - det));
    radii_out[n] = valid ? ceilf(3.0f * sqrtf(lam1)) : 0.0f;

    float gx = ((pp0 + 1.0f) * (float)W_IMG - 1.0f) * 0.5f;
    float gy = ((pp1 + 1.0f) * (float)H_IMG - 1.0f) * 0.5f;

    float dxm = mx - campos[0], dym = my - campos[1], dzm = mz - campos[2];
    float dn = sqrtf(dxm*dxm + dym*dym + dzm*dzm);
    float sx = dxm/dn, sy = dym/dn, sz = dzm/dn;
    float xx = sx*sx, yy = sy*sy, zz = sz*sz;
    float xy = sx*sy, yz = sy*sz, xz = sx*sz;
    const float4* sh4 = (const float4*)(shs + n*48);
    float shf[48];
    #pragma unroll
    for (int k = 0; k < 12; ++k) {
        float4 v = sh4[k];
        shf[k*4+0]=v.x; shf[k*4+1]=v.y; shf[k*4+2]=v.z; shf[k*4+3]=v.w;
    }
    float col[3];
    #pragma unroll
    for (int ch = 0; ch < 3; ++ch) {
        float res = 0.28209479177387814f * shf[0*3+ch]
            - 0.4886025119029199f * sy * shf[1*3+ch]
            + 0.4886025119029199f * sz * shf[2*3+ch]
            - 0.4886025119029199f * sx * shf[3*3+ch]
            + 1.0925484305920792f  * xy * shf[4*3+ch]
            + (-1.0925484305920792f) * yz * shf[5*3+ch]
            + 0.31539156525252005f * (2.f*zz - xx - yy) * shf[6*3+ch]
            + (-1.0925484305920792f) * xz * shf[7*3+ch]
            + 0.5462742152960396f  * (xx - yy) * shf[8*3+ch]
            + (-0.5900435899266435f) * sy * (3.f*xx - yy) * shf[9*3+ch]
            + 2.890611442640554f   * xy * sz * shf[10*3+ch]
            + (-0.4570457994644658f) * sy * (4.f*zz - xx - yy) * shf[11*3+ch]
            + 0.3731763325901154f  * sz * (2.f*zz - 3.f*xx - 3.f*yy) * shf[12*3+ch]
            + (-0.4570457994644658f) * sx * (4.f*zz - xx - yy) * shf[13*3+ch]
            + 1.445305721320277f   * sz * (xx - yy) * shf[14*3+ch]
            + (-0.5900435899266435f) * sx * (xx - 3.f*yy) * shf[15*3+ch];
        col[ch] = fmaxf(res + 0.5f, 0.0f);
    }

    float op = opac[n];
    float op255 = op * 255.0f;
    float rc2 = (valid && op255 > 1.0f) ? (2.0f * logf(op255) * lam1 * 1.01f + 1.0f)
                                        : -1.0f;

    payload[n*3+0] = make_float4(gx, gy, conA, conB);
    payload[n*3+1] = make_float4(conC, op, col[0], col[1]);
    payload[n*3+2] = make_float4(col[2], rc2, 0.f, 0.f);

    unsigned int kb = valid ? __float_as_uint(depth) : 0x7F800000u;
    keys[n] = ((unsigned long long)kb << 32) | (unsigned int)n;
}

// ---------------- Kernel 2: LDS-staged rank sort + scatter ----------------
__global__ __launch_bounds__(256) void rank_sort_kernel(
    const unsigned long long* __restrict__ keys,
    const float4* __restrict__ payload,
    float4* __restrict__ sorted_payload)
{
    __shared__ unsigned long long k_lds[N_G];
    const int t = threadIdx.x;
    const int n = blockIdx.x * 256 + t;

    #pragma unroll
    for (int i = 0; i < N_G / 256; ++i)
        k_lds[t + i * 256] = keys[t + i * 256];
    __syncthreads();

    unsigned long long mine = k_lds[n];
    int rank = 0;
    #pragma unroll 16
    for (int j = 0; j < N_G; ++j)
        rank += (k_lds[j] < mine) ? 1 : 0;    // keys unique (idx in low bits)

    float4 p0 = payload[n*3+0], p1 = payload[n*3+1], p2 = payload[n*3+2];
    sorted_payload[rank*3+0] = p0;
    sorted_payload[rank*3+1] = p1;
    sorted_payload[rank*3+2] = p2;
}

// ---------------- Kernel 3: per-tile streaming cull + pipelined blend ----------------
__global__ __launch_bounds__(64) void raster_tile(
    const float4* __restrict__ pay,       // sorted, 3 float4 per gaussian
    const float* __restrict__ bg,
    float* __restrict__ out)
{
    __shared__ float batch[(64 + 4) * 16];   // stride 16 floats; +4 slots for padding

    const int lane = threadIdx.x;
    const int tile = blockIdx.x;
    const int tx = tile & (TILES_X - 1), ty = tile / TILES_X;
    const float x0 = (float)(tx * TILE), x1 = x0 + (float)(TILE - 1);
    const float y0 = (float)(ty * TILE), y1 = y0 + (float)(TILE - 1);
    const float px = x0 + (float)(lane & (TILE - 1));
    const float py = y0 + (float)(lane / TILE);

    float T = 1.0f, Tfin = 1.0f, cr = 0.f, cg = 0.f, cb = 0.f;
    bool live = true;

    // prefetch chunk 0
    float4 a0 = pay[lane*3+0], a1 = pay[lane*3+1], a2 = pay[lane*3+2];

    for (int base = 0; base < N_G; base += 64) {
        // prefetch next chunk while processing this one
        float4 n0, n1, n2;
        if (base + 64 < N_G) {
            const float4* np = pay + (base + 64 + lane) * 3;
            n0 = np[0]; n1 = np[1]; n2 = np[2];
        }

        // cull from registers (rc2 in a2.y; invalid records carry rc2 = -1)
        float cx = fminf(fmaxf(a0.x, x0), x1) - a0.x;
        float cy = fminf(fmaxf(a0.y, y0), y1) - a0.y;
        bool pass = (cx*cx + cy*cy) <= a2.y;
        unsigned long long mask = __ballot(pass);

        if (mask != 0ull) {
            int pos = __popcll(mask & ((1ull << lane) - 1ull));
            if (pass) {
                float4* bp = (float4*)(batch + pos * 16);
                bp[0] = a0; bp[1] = a1; bp[2] = a2;
            }
            int nb  = __popcll(mask);
            int nb4 = (nb + 3) & ~3;
            if (lane < nb4 - nb) {
                // dummy record: op=0 -> alpha=0 -> exactly skipped
                float4* bp = (float4*)(batch + (nb + lane) * 16);
                bp[0] = make_float4(0.f, 0.f, 0.f, 0.f);
                bp[1] = make_float4(0.f, 0.f, 0.f, 0.f);
                bp[2] = make_float4(0.f, 0.f, 0.f, 0.f);
            }
            __syncthreads();

            for (int j = 0; j < nb4; j += 4) {
                float4 g0[4], g1[4];
                float  b2[4], alpha[4];
                bool   ok[4];
                #pragma unroll
                for (int u = 0; u < 4; ++u) {
                    const float* bp = batch + (j + u) * 16;
                    g0[u] = *(const float4*)(bp);
                    g1[u] = *(const float4*)(bp + 4);
                    b2[u] = bp[8];
                }
                #pragma unroll
                for (int u = 0; u < 4; ++u) {
                    float dx = g0[u].x - px, dy = g0[u].y - py;
                    float power = -0.5f * (g0[u].z*dx*dx + g1[u].x*dy*dy) - g0[u].w*dx*dy;
                    alpha[u] = fminf(0.99f, g1[u].y * __expf(power));
                    ok[u] = (power <= 0.0f) && (alpha[u] >= (1.0f/255.0f));
                }
                #pragma unroll
                for (int u = 0; u < 4; ++u) {
                    if (live && ok[u]) {
                        float Tnew = T * (1.0f - alpha[u]);
                        if (Tnew < 1e-4f) {
                            live = false;     // exact: ae_i and all later ae are 0
                        } else {
                            float w = T * alpha[u];
                            cr += w * g1[u].z; cg += w * g1[u].w; cb += w * b2[u];
                            Tfin *= (1.0f - alpha[u]);
                            T = Tnew;
                        }
                    }
                }
            }
            __syncthreads();
            if (__ballot(live) == 0ull) break;
        }

        a0 = n0; a1 = n1; a2 = n2;
    }

    int p = (int)py * W_IMG + (int)px;
    out[p]                 = cr + bg[0] * Tfin;
    out[H_IMG*W_IMG + p]   = cg + bg[1] * Tfin;
    out[2*H_IMG*W_IMG + p] = cb + bg[2] * Tfin;
}

extern "C" void kernel_launch(void* const* d_in, const int* in_sizes, int n_in,
                              void* d_out, int out_size, void* d_ws, size_t ws_size,
                              hipStream_t stream) {
    const float* means3D = (const float*)d_in[0];
    const float* opac    = (const float*)d_in[2];
    const float* shs     = (const float*)d_in[3];
    const float* scales  = (const float*)d_in[4];
    const float* rot     = (const float*)d_in[5];
    const float* vm      = (const float*)d_in[6];
    const float* pm      = (const float*)d_in[7];
    const float* campos  = (const float*)d_in[8];
    const float* bg      = (const float*)d_in[9];

    float* out = (float*)d_out;
    float* wsf = (float*)d_ws;
    float4*             payload = (float4*)(wsf + WS_PAY);
    float4*             sorted  = (float4*)(wsf + WS_SORTED);
    unsigned long long* keys    = (unsigned long long*)(wsf + WS_KEYS);

    prep_kernel<<<N_G/64, 64, 0, stream>>>(means3D, opac, shs, scales, rot,
                                           vm, pm, campos,
                                           out + 3*H_IMG*W_IMG, payload, keys);
    rank_sort_kernel<<<N_G/256, 256, 0, stream>>>(keys, payload, sorted);
    raster_tile<<<N_TILES, 64, 0, stream>>>(sorted, bg, out);
}